// Round 3
// baseline (500.930 us; speedup 1.0000x reference)
//
#include <hip/hip_runtime.h>
#include <hip/hip_bf16.h>

// Problem constants (from reference)
#define NW   8192
#define NS   8192
#define FD   1024
#define EMB  128
#define QN   1024
#define NC   80

// ---------- workspace layout (element offsets, 4B units) ----------
#define OFF_Q      0u                       // float [NW*EMB]
#define OFF_K      1048576u                 // float [NS*EMB]
#define OFF_TABLE  2097152u                 // int   [NC*8192]
#define OFF_HIST   2752512u                 // int   [128]  (NC used)
#define OFF_RANK   2752640u                 // int   [NW]
#define OFF_OCC    2760832u                 // int   [NS]
#define OFF_IDX    2769024u                 // int   [NW]
#define OFF_LPOS   2777216u                 // float [NW]
#define OFF_BHS    2785408u                 // int   [32*NC]
#define OFF_BHW    2787968u                 // int   [32*NC]
#define OFF_ACC    2790528u                 // float [2] : {sum_ce, valid_count}

// ---------------- init: zero hist + accum ----------------
__global__ void zero_k(int* hist, float* accum) {
    int t = threadIdx.x;
    if (t < 128) hist[t] = 0;
    if (t < 2) accum[t] = 0.0f;
}

// ---------------- strong-label histogram ----------------
__global__ void hist_k(const int* __restrict__ s, int* __restrict__ hist) {
    int j = blockIdx.x * 256 + threadIdx.x;
    if (j < NS) atomicAdd(&hist[s[j]], 1);
}

// ---------------- per-block class histograms (for rank/occ) ----------------
__global__ void blockhist_k(const int* __restrict__ lab, int* __restrict__ bh) {
    __shared__ int h[NC];
    int t = threadIdx.x;
    if (t < NC) h[t] = 0;
    __syncthreads();
    int j = blockIdx.x * 256 + t;
    atomicAdd(&h[lab[j]], 1);
    __syncthreads();
    if (t < NC) bh[blockIdx.x * NC + t] = h[t];
}

// ---------------- rank[j] = #{j' < j : lab[j']==lab[j]} ----------------
__global__ void rank_k(const int* __restrict__ lab, const int* __restrict__ bh,
                       int* __restrict__ out) {
    __shared__ int ll[256];
    int t = threadIdx.x;
    int j = blockIdx.x * 256 + t;
    int c = lab[j];
    ll[t] = c;
    __syncthreads();
    int r = 0;
    for (int b = 0; b < blockIdx.x; b++) r += bh[b * NC + c];
    for (int jj = 0; jj < t; jj++) r += (ll[jj] == c) ? 1 : 0;
    out[j] = r;
}

// ---------------- table[c][occ] = strong index ----------------
__global__ void table_k(const int* __restrict__ s, const int* __restrict__ occ,
                        int* __restrict__ table) {
    int j = blockIdx.x * 256 + threadIdx.x;
    if (j < NS) table[s[j] * 8192 + occ[j]] = j;
}

// ---------------- idx[i] = table[w[i]][rank[i] % cnt] ----------------
__global__ void idx_k(const int* __restrict__ w, const int* __restrict__ rank,
                      const int* __restrict__ hist, const int* __restrict__ table,
                      int* __restrict__ idx) {
    int i = blockIdx.x * 256 + threadIdx.x;
    if (i < NW) {
        int c = w[i];
        int cc = hist[c];
        idx[i] = (cc > 0) ? table[c * 8192 + (rank[i] % cc)] : 0;
    }
}

// ---------------- encoder GEMM: out[M][128] = A[M][1024] @ W[1024][128] + b ----------------
// grid: M/8 blocks, 128 threads; 8 rows per block, A staged to LDS via float4.
__global__ __launch_bounds__(128) void enc_gemm_k(const float* __restrict__ A,
                                                  const float* __restrict__ W,
                                                  const float* __restrict__ bias,
                                                  float* __restrict__ out) {
    __shared__ float a_lds[8][FD];   // 32 KB
    int t = threadIdx.x;             // 0..127 = output column
    int row0 = blockIdx.x * 8;

    const float4* Av = (const float4*)(A + (size_t)row0 * FD);   // 4 floats per float4
    for (int v = t; v < (8 * FD) / 4; v += 128) {
        float4 u = Av[v];
        int e = v * 4;
        float* dst = &a_lds[e >> 10][e & 1023];
        dst[0] = u.x; dst[1] = u.y; dst[2] = u.z; dst[3] = u.w;
    }
    __syncthreads();

    float acc[8];
    float bv = bias[t];
#pragma unroll
    for (int r = 0; r < 8; r++) acc[r] = bv;

    for (int kk = 0; kk < FD; kk += 4) {
        float w0 = W[(kk + 0) * EMB + t];
        float w1 = W[(kk + 1) * EMB + t];
        float w2 = W[(kk + 2) * EMB + t];
        float w3 = W[(kk + 3) * EMB + t];
#pragma unroll
        for (int r = 0; r < 8; r++) {
            float4 av = *(const float4*)&a_lds[r][kk];
            acc[r] += av.x * w0 + av.y * w1 + av.z * w2 + av.w * w3;
        }
    }
#pragma unroll
    for (int r = 0; r < 8; r++) out[(size_t)(row0 + r) * EMB + t] = acc[r];
}

// ---------------- l_pos[i] = dot(q[i], k[idx[i]]) ----------------
__global__ __launch_bounds__(128) void lpos_k(const float* __restrict__ q,
                                              const float* __restrict__ k,
                                              const int* __restrict__ idx,
                                              float* __restrict__ lpos) {
    int i = blockIdx.x;
    int t = threadIdx.x;
    float p = q[(size_t)i * EMB + t] * k[(size_t)idx[i] * EMB + t];
    for (int o = 32; o > 0; o >>= 1) p += __shfl_down(p, o);
    __shared__ float s2[2];
    if ((t & 63) == 0) s2[t >> 6] = p;
    __syncthreads();
    if (t == 0) lpos[i] = s2[0] + s2[1];
}

// ---------------- fused l_neg + CE + masked accumulate ----------------
// grid: NW/8 blocks, 256 threads (4 waves). Each thread owns cols 4t..4t+3.
__global__ __launch_bounds__(256) void ce_k(const float* __restrict__ q,
                                            const float* __restrict__ queue,
                                            const float* __restrict__ lpos,
                                            const int* __restrict__ w,
                                            const int* __restrict__ hist,
                                            float* __restrict__ accum) {
    __shared__ float q_lds[8][EMB];   // 4 KB
    __shared__ float logit[8][QN];    // 32 KB
    int t = threadIdx.x;
    int i0 = blockIdx.x * 8;

    for (int v = t; v < 8 * EMB; v += 256)
        q_lds[v >> 7][v & 127] = q[(size_t)i0 * EMB + v];
    __syncthreads();

    float acc[8][4];
#pragma unroll
    for (int r = 0; r < 8; r++)
#pragma unroll
        for (int c = 0; c < 4; c++) acc[r][c] = 0.0f;

    // B[e][n] = queue_flat[e*1024 + n]; this thread's n = 4t..4t+3
    const float4* Qv = (const float4*)queue;
    for (int e = 0; e < EMB; e++) {
        float4 u = Qv[e * 256 + t];
#pragma unroll
        for (int r = 0; r < 8; r++) {
            float qv = q_lds[r][e];
            acc[r][0] += qv * u.x;
            acc[r][1] += qv * u.y;
            acc[r][2] += qv * u.z;
            acc[r][3] += qv * u.w;
        }
    }
#pragma unroll
    for (int r = 0; r < 8; r++)
        *(float4*)&logit[r][4 * t] = make_float4(acc[r][0], acc[r][1], acc[r][2], acc[r][3]);
    __syncthreads();

    // per-row logsumexp: wave wv handles rows wv and wv+4
    int wv = t >> 6, ln = t & 63;
    for (int rr = 0; rr < 2; rr++) {
        int r = wv + rr * 4;
        int i = i0 + r;
        float lp = lpos[i];
        float vbuf[16];
        float m = lp;
#pragma unroll
        for (int u2 = 0; u2 < 16; u2++) {
            float v = logit[r][ln + u2 * 64];
            vbuf[u2] = v;
            m = fmaxf(m, v);
        }
        for (int o = 32; o > 0; o >>= 1) m = fmaxf(m, __shfl_down(m, o));
        m = __shfl(m, 0);
        float s = 0.0f;
#pragma unroll
        for (int u2 = 0; u2 < 16; u2++) s += expf(vbuf[u2] - m);
        for (int o = 32; o > 0; o >>= 1) s += __shfl_down(s, o);
        if (ln == 0) {
            s += expf(lp - m);
            float ce = -(lp - m - logf(s));
            if (hist[w[i]] > 0) {
                atomicAdd(&accum[0], ce);
                atomicAdd(&accum[1], 1.0f);
            }
        }
    }
}

// ---------------- finalize: loss = sum / max(count,1) -> float32 out ----------------
__global__ void final_k(const float* __restrict__ accum, float* __restrict__ out) {
    if (threadIdx.x == 0 && blockIdx.x == 0) {
        out[0] = accum[0] / fmaxf(accum[1], 1.0f);
    }
}

extern "C" void kernel_launch(void* const* d_in, const int* in_sizes, int n_in,
                              void* d_out, int out_size, void* d_ws, size_t ws_size,
                              hipStream_t stream) {
    const float* feats_strong = (const float*)d_in[0];
    const float* feats_weak   = (const float*)d_in[1];
    const int*   s_lab        = (const int*)d_in[2];
    const int*   w_lab        = (const int*)d_in[3];
    const float* Wq           = (const float*)d_in[4];
    const float* bq           = (const float*)d_in[5];
    const float* Wk           = (const float*)d_in[6];
    const float* bk           = (const float*)d_in[7];
    const float* queue        = (const float*)d_in[8];

    float* wsf = (float*)d_ws;
    int*   wsi = (int*)d_ws;

    float* q_g    = wsf + OFF_Q;
    float* k_g    = wsf + OFF_K;
    int*   table  = wsi + OFF_TABLE;
    int*   hist   = wsi + OFF_HIST;
    int*   rank   = wsi + OFF_RANK;
    int*   occ    = wsi + OFF_OCC;
    int*   idx    = wsi + OFF_IDX;
    float* lpos   = wsf + OFF_LPOS;
    int*   bhs    = wsi + OFF_BHS;
    int*   bhw    = wsi + OFF_BHW;
    float* accum  = wsf + OFF_ACC;

    zero_k<<<1, 128, 0, stream>>>(hist, accum);
    hist_k<<<NS / 256, 256, 0, stream>>>(s_lab, hist);
    blockhist_k<<<NS / 256, 256, 0, stream>>>(s_lab, bhs);
    rank_k<<<NS / 256, 256, 0, stream>>>(s_lab, bhs, occ);
    blockhist_k<<<NW / 256, 256, 0, stream>>>(w_lab, bhw);
    rank_k<<<NW / 256, 256, 0, stream>>>(w_lab, bhw, rank);
    table_k<<<NS / 256, 256, 0, stream>>>(s_lab, occ, table);
    idx_k<<<NW / 256, 256, 0, stream>>>(w_lab, rank, hist, table, idx);

    enc_gemm_k<<<NW / 8, 128, 0, stream>>>(feats_weak, Wq, bq, q_g);
    enc_gemm_k<<<NS / 8, 128, 0, stream>>>(feats_strong, Wk, bk, k_g);

    lpos_k<<<NW, 128, 0, stream>>>(q_g, k_g, idx, lpos);
    ce_k<<<NW / 8, 256, 0, stream>>>(q_g, queue, lpos, w_lab, hist, accum);
    final_k<<<1, 64, 0, stream>>>(accum, (float*)d_out);
}

// Round 4
// 212.300 us; speedup vs baseline: 2.3595x; 2.3595x over previous
//
#include <hip/hip_runtime.h>
#include <hip/hip_bf16.h>

// Problem constants (from reference)
#define NW   8192
#define NS   8192
#define FD   1024
#define EMB  128
#define QN   1024
#define NC   80

typedef unsigned short ushort_t;
typedef unsigned int   uint_t;
typedef __attribute__((ext_vector_type(8))) short short8;
typedef __attribute__((ext_vector_type(4))) float f32x4;

// ---------- workspace layout (element offsets, 4B units) ----------
#define OFF_Q      0u           // float [NW*EMB]                     (4 MB)
#define OFF_K      1048576u     // float [NS*EMB]                     (4 MB)
#define OFF_TABLE  2097152u     // int   [NC*8192]  (2.62 MB) — ALSO aliases Wt_q/Wt_k (see order)
#define OFF_WTQ    2097152u     // ushort[128K] = 32768 uint units (aliases table; enc runs before table_k)
#define OFF_WTK    2129920u     // ushort[128K] = 32768 uint units
#define OFF_HIST   2752512u     // int   [128]
#define OFF_RANK   2752640u     // int   [NW]
#define OFF_OCC    2760832u     // int   [NS]
#define OFF_IDX    2769024u     // int   [NW]
#define OFF_LPOS   2777216u     // float [NW]
#define OFF_BHS    2785408u     // int   [32*NC]
#define OFF_BHW    2787968u     // int   [32*NC]
#define OFF_ACC    2790528u     // float [2] : {sum_ce, valid_count}
#define OFF_QT     2790532u     // ushort[1024*128] = 32768 uint units (Qt: queue^T bf16)

__device__ __forceinline__ ushort_t f2bf(float f) {   // fp32 -> bf16 RNE
    uint_t u = __float_as_uint(f);
    u = (u + 0x7fffu + ((u >> 16) & 1u)) >> 16;
    return (ushort_t)u;
}
__device__ __forceinline__ uint_t pack2(float a, float b) {
    return (uint_t)f2bf(a) | ((uint_t)f2bf(b) << 16);
}

// ---------------- init: zero hist + accum ----------------
__global__ void zero_k(int* hist, float* accum) {
    int t = threadIdx.x;
    if (t < 128) hist[t] = 0;
    if (t < 2) accum[t] = 0.0f;
}

// ---------------- strong-label histogram ----------------
__global__ void hist_k(const int* __restrict__ s, int* __restrict__ hist) {
    int j = blockIdx.x * 256 + threadIdx.x;
    if (j < NS) atomicAdd(&hist[s[j]], 1);
}

// ---------------- per-block class histograms (for rank/occ) ----------------
__global__ void blockhist_k(const int* __restrict__ lab, int* __restrict__ bh) {
    __shared__ int h[NC];
    int t = threadIdx.x;
    if (t < NC) h[t] = 0;
    __syncthreads();
    int j = blockIdx.x * 256 + t;
    atomicAdd(&h[lab[j]], 1);
    __syncthreads();
    if (t < NC) bh[blockIdx.x * NC + t] = h[t];
}

// ---------------- rank[j] = #{j' < j : lab[j']==lab[j]} ----------------
__global__ void rank_k(const int* __restrict__ lab, const int* __restrict__ bh,
                       int* __restrict__ out) {
    __shared__ int ll[256];
    int t = threadIdx.x;
    int j = blockIdx.x * 256 + t;
    int c = lab[j];
    ll[t] = c;
    __syncthreads();
    int r = 0;
    for (int b = 0; b < blockIdx.x; b++) r += bh[b * NC + c];
    for (int jj = 0; jj < t; jj++) r += (ll[jj] == c) ? 1 : 0;
    out[j] = r;
}

// ---------------- table[c][occ] = strong index ----------------
__global__ void table_k(const int* __restrict__ s, const int* __restrict__ occ,
                        int* __restrict__ table) {
    int j = blockIdx.x * 256 + threadIdx.x;
    if (j < NS) table[s[j] * 8192 + occ[j]] = j;
}

// ---------------- idx[i] = table[w[i]][rank[i] % cnt] ----------------
__global__ void idx_k(const int* __restrict__ w, const int* __restrict__ rank,
                      const int* __restrict__ hist, const int* __restrict__ table,
                      int* __restrict__ idx) {
    int i = blockIdx.x * 256 + threadIdx.x;
    if (i < NW) {
        int c = w[i];
        int cc = hist[c];
        idx[i] = (cc > 0) ? table[c * 8192 + (rank[i] % cc)] : 0;
    }
}

// ---------------- convert+transpose: W -> Wt (tiled bf16), queue -> Qt (bf16) ----------------
// z=0: Wq[1024][128] -> Wtq[kb][n][kk]  (kb=k>>5, kk=k&31)
// z=1: Wk          -> Wtk same
// z=2: queue[128][1024] -> Qt[n=1024][k=128] plain
__global__ __launch_bounds__(256) void cvt_k(const float* __restrict__ Wq,
                                             const float* __restrict__ Wk,
                                             const float* __restrict__ queue,
                                             ushort_t* __restrict__ Wtq,
                                             ushort_t* __restrict__ Wtk,
                                             ushort_t* __restrict__ Qt) {
    __shared__ float tile[32][33];
    int z = blockIdx.y, flat = blockIdx.x;
    const float* in; ushort_t* out; int r0, c0, C;
    if (z < 2) { in = z ? Wk : Wq; out = z ? Wtk : Wtq; C = 128;
                 r0 = (flat >> 2) * 32; c0 = (flat & 3) * 32; }
    else       { in = queue; out = Qt; C = 1024;
                 r0 = (flat & 3) * 32; c0 = (flat >> 2) * 32; }
    int t = threadIdx.x;
    int i = t >> 3, j0 = (t & 7) * 4;
    float4 v = *(const float4*)(in + (size_t)(r0 + i) * C + c0 + j0);
    tile[i][j0] = v.x; tile[i][j0 + 1] = v.y; tile[i][j0 + 2] = v.z; tile[i][j0 + 3] = v.w;
    __syncthreads();
    // out[n = c0+i][k = r0+j0+x] = tile[j0+x][i]
    uint2 pk;
    pk.x = pack2(tile[j0][i], tile[j0 + 1][i]);
    pk.y = pack2(tile[j0 + 2][i], tile[j0 + 3][i]);
    size_t oaddr;
    if (z < 2) oaddr = ((size_t)(r0 >> 5) * 128 + (c0 + i)) * 32 + j0;   // tiled [kb][n][kk]
    else       oaddr = (size_t)(c0 + i) * 128 + (r0 + j0);               // plain [n][k]
    *(uint2*)(out + oaddr) = pk;
}

// ---------------- fused encoder GEMM (MFMA): out[M][128] = A[M][1024]@W + b ----------------
// grid 256: bx>>7 selects encoder, bx&127 = M-tile of 64. 256 thr = 4 waves (2x2).
__global__ __launch_bounds__(256) void enc_mfma_k(const float* __restrict__ A0,
                                                  const float* __restrict__ A1,
                                                  const ushort_t* __restrict__ Wt0,
                                                  const ushort_t* __restrict__ Wt1,
                                                  const float* __restrict__ b0,
                                                  const float* __restrict__ b1,
                                                  float* __restrict__ out0,
                                                  float* __restrict__ out1) {
    __shared__ __align__(16) ushort_t Alds[64][40];    // 64 rows x BK=32 (+8 pad)
    __shared__ __align__(16) ushort_t Blds[128][40];   // 128 cols x BK=32 (+8 pad)

    int bx = blockIdx.x;
    int which = bx >> 7;
    int mtile = bx & 127;
    const float*    A    = which ? A1 : A0;
    const ushort_t* Wt   = which ? Wt1 : Wt0;
    const float*    bias = which ? b1 : b0;
    float*          out  = which ? out1 : out0;
    int row0 = mtile * 64;

    int t = threadIdx.x;
    int wv = t >> 6, ln = t & 63;
    int wm = wv >> 1, wn = wv & 1;
    int lane15 = ln & 15, kg = ln >> 4;

    // staging indices
    int sm = t >> 2;             // A row 0..63
    int sk = (t & 3) * 8;        // A k-offset 0,8,16,24
    int bn = t >> 1;             // B col 0..127
    int bk = (t & 1) * 16;       // B k-offset 0,16

    f32x4 acc[2][4];
#pragma unroll
    for (int a = 0; a < 2; a++)
#pragma unroll
        for (int b = 0; b < 4; b++) acc[a][b] = (f32x4){0.f, 0.f, 0.f, 0.f};

    float4 pa0, pa1; uint4 pb0, pb1;
    {
        const float4* p = (const float4*)(A + (size_t)(row0 + sm) * FD + sk);
        pa0 = p[0]; pa1 = p[1];
        const uint4* pw = (const uint4*)(Wt + bn * 32 + bk);
        pb0 = pw[0]; pb1 = pw[1];
    }

    for (int kb = 0; kb < 32; kb++) {
        // commit staged regs to LDS (bf16 convert A)
        uint4 pk;
        pk.x = pack2(pa0.x, pa0.y); pk.y = pack2(pa0.z, pa0.w);
        pk.z = pack2(pa1.x, pa1.y); pk.w = pack2(pa1.z, pa1.w);
        *(uint4*)&Alds[sm][sk] = pk;
        *(uint4*)&Blds[bn][bk] = pb0;
        *(uint4*)&Blds[bn][bk + 8] = pb1;
        __syncthreads();
        if (kb < 31) {
            const float4* p = (const float4*)(A + (size_t)(row0 + sm) * FD + (kb + 1) * 32 + sk);
            pa0 = p[0]; pa1 = p[1];
            const uint4* pw = (const uint4*)(Wt + (size_t)(kb + 1) * 4096 + bn * 32 + bk);
            pb0 = pw[0]; pb1 = pw[1];
        }
        short8 af[2];
#pragma unroll
        for (int m2 = 0; m2 < 2; m2++)
            af[m2] = __builtin_bit_cast(short8, *(const uint4*)&Alds[wm * 32 + m2 * 16 + lane15][kg * 8]);
#pragma unroll
        for (int nt = 0; nt < 4; nt++) {
            short8 bf = __builtin_bit_cast(short8, *(const uint4*)&Blds[wn * 64 + nt * 16 + lane15][kg * 8]);
#pragma unroll
            for (int m2 = 0; m2 < 2; m2++)
                acc[m2][nt] = __builtin_amdgcn_mfma_f32_16x16x32_bf16(af[m2], bf, acc[m2][nt], 0, 0, 0);
        }
        __syncthreads();
    }

    // epilogue: C[row][col], row=(lane>>4)*4+reg, col=lane&15  [m89/m91-verified]
#pragma unroll
    for (int m2 = 0; m2 < 2; m2++)
#pragma unroll
        for (int nt = 0; nt < 4; nt++) {
            int col = wn * 64 + nt * 16 + lane15;
            float bv = bias[col];
            int rbase = row0 + wm * 32 + m2 * 16 + kg * 4;
#pragma unroll
            for (int j = 0; j < 4; j++)
                out[(size_t)(rbase + j) * EMB + col] = acc[m2][nt][j] + bv;
        }
}

// ---------------- l_pos[i] = dot(q[i], k[idx[i]]) (fp32) ----------------
__global__ __launch_bounds__(256) void lpos_k(const float* __restrict__ q,
                                              const float* __restrict__ k,
                                              const int* __restrict__ idx,
                                              float* __restrict__ lpos) {
    int t = threadIdx.x;
    int r = blockIdx.x * 32 + (t >> 3);
    int o = (t & 7) * 16;
    const float4* qa = (const float4*)(q + (size_t)r * EMB + o);
    const float4* ka = (const float4*)(k + (size_t)idx[r] * EMB + o);
    float s = 0.f;
#pragma unroll
    for (int p = 0; p < 4; p++) {
        float4 a = qa[p], b = ka[p];
        s += a.x * b.x + a.y * b.y + a.z * b.z + a.w * b.w;
    }
    s += __shfl_xor(s, 1); s += __shfl_xor(s, 2); s += __shfl_xor(s, 4);
    if ((t & 7) == 0) lpos[r] = s;
}

// ---------------- fused l_neg (MFMA) + online-softmax CE ----------------
// grid 256 blocks: 32 q-rows each. 256 thr = 4 waves 2x2: wm=row-half, wn=col-half of 128-chunk.
__global__ __launch_bounds__(256) void ce_mfma_k(const float* __restrict__ q,
                                                 const ushort_t* __restrict__ Qt,
                                                 const float* __restrict__ lpos,
                                                 const int* __restrict__ w,
                                                 const int* __restrict__ hist,
                                                 float* __restrict__ accum) {
    __shared__ __align__(16) ushort_t Alds[32][136];    // q rows x K=128 (+8 pad)
    __shared__ __align__(16) ushort_t Blds[128][136];   // queue cols x K=128 (+8 pad)
    __shared__ float mg[2][32][2];                      // [wn][row][{m,l}]

    int t = threadIdx.x;
    int wv = t >> 6, ln = t & 63;
    int wm = wv >> 1, wn = wv & 1;
    int lane15 = ln & 15, kg = ln >> 4;
    int r0 = blockIdx.x * 32;

    // stage A (q rows, fp32 -> bf16): thread: row t>>3, k-off (t&7)*16
    {
        int m = t >> 3, off = (t & 7) * 16;
        const float4* p = (const float4*)(q + (size_t)(r0 + m) * EMB + off);
        float4 v0 = p[0], v1 = p[1], v2 = p[2], v3 = p[3];
        uint4 pk0, pk1;
        pk0.x = pack2(v0.x, v0.y); pk0.y = pack2(v0.z, v0.w);
        pk0.z = pack2(v1.x, v1.y); pk0.w = pack2(v1.z, v1.w);
        pk1.x = pack2(v2.x, v2.y); pk1.y = pack2(v2.z, v2.w);
        pk1.z = pack2(v3.x, v3.y); pk1.w = pack2(v3.z, v3.w);
        *(uint4*)&Alds[m][off] = pk0;
        *(uint4*)&Alds[m][off + 8] = pk1;
    }
    __syncthreads();

    // load a-frags once: wave's 16 rows, 4 K-steps
    short8 afr[4];
#pragma unroll
    for (int ks = 0; ks < 4; ks++)
        afr[ks] = __builtin_bit_cast(short8, *(const uint4*)&Alds[wm * 16 + lane15][ks * 32 + kg * 8]);

    float run_m[4], run_l[4];
#pragma unroll
    for (int j = 0; j < 4; j++) { run_m[j] = -1e30f; run_l[j] = 0.f; }

    // B prefetch regs: 128 B per thread per chunk
    uint4 pb[8];
    {
        const uint4* p = (const uint4*)(Qt + (size_t)(t >> 1) * 128 + (t & 1) * 64);
#pragma unroll
        for (int p8 = 0; p8 < 8; p8++) pb[p8] = p[p8];
    }

    for (int nc = 0; nc < 8; nc++) {
#pragma unroll
        for (int p8 = 0; p8 < 8; p8++)
            *(uint4*)&Blds[t >> 1][(t & 1) * 64 + p8 * 8] = pb[p8];
        __syncthreads();
        if (nc < 7) {
            const uint4* p = (const uint4*)(Qt + (size_t)((nc + 1) * 128 + (t >> 1)) * 128 + (t & 1) * 64);
#pragma unroll
            for (int p8 = 0; p8 < 8; p8++) pb[p8] = p[p8];
        }
        f32x4 acc[4];
#pragma unroll
        for (int nt = 0; nt < 4; nt++) acc[nt] = (f32x4){0.f, 0.f, 0.f, 0.f};
#pragma unroll
        for (int nt = 0; nt < 4; nt++)
#pragma unroll
            for (int ks = 0; ks < 4; ks++) {
                short8 bf = __builtin_bit_cast(short8,
                    *(const uint4*)&Blds[wn * 64 + nt * 16 + lane15][ks * 32 + kg * 8]);
                acc[nt] = __builtin_amdgcn_mfma_f32_16x16x32_bf16(afr[ks], bf, acc[nt], 0, 0, 0);
            }
        __syncthreads();   // before next chunk's staging overwrites Blds

        // online softmax update; lane's rows = kg*4+j, cols = wn*64 + nt*16 + lane15
#pragma unroll
        for (int j = 0; j < 4; j++) {
            float v0 = acc[0][j], v1 = acc[1][j], v2 = acc[2][j], v3 = acc[3][j];
            float mc = fmaxf(fmaxf(v0, v1), fmaxf(v2, v3));
            mc = fmaxf(mc, __shfl_xor(mc, 1));
            mc = fmaxf(mc, __shfl_xor(mc, 2));
            mc = fmaxf(mc, __shfl_xor(mc, 4));
            mc = fmaxf(mc, __shfl_xor(mc, 8));
            float nm = fmaxf(run_m[j], mc);
            float s = __expf(v0 - nm) + __expf(v1 - nm) + __expf(v2 - nm) + __expf(v3 - nm);
            s += __shfl_xor(s, 1);
            s += __shfl_xor(s, 2);
            s += __shfl_xor(s, 4);
            s += __shfl_xor(s, 8);
            run_l[j] = run_l[j] * __expf(run_m[j] - nm) + s;
            run_m[j] = nm;
        }
    }

    // merge across wn halves + l_pos, then block-reduce CE
    if (lane15 == 0) {
#pragma unroll
        for (int j = 0; j < 4; j++) {
            int rl = wm * 16 + kg * 4 + j;
            mg[wn][rl][0] = run_m[j];
            mg[wn][rl][1] = run_l[j];
        }
    }
    __syncthreads();
    if (wv == 0) {
        float cv = 0.f, cc = 0.f;
        if (t < 32) {
            int i = r0 + t;
            float m0 = mg[0][t][0], l0 = mg[0][t][1];
            float m1 = mg[1][t][0], l1 = mg[1][t][1];
            float lp = lpos[i];
            float m = fmaxf(fmaxf(m0, m1), lp);
            float l = l0 * __expf(m0 - m) + l1 * __expf(m1 - m) + __expf(lp - m);
            float ce = -(lp - m - __logf(l));
            if (hist[w[i]] > 0) { cv = ce; cc = 1.f; }
        }
        cv += __shfl_xor(cv, 1);  cc += __shfl_xor(cc, 1);
        cv += __shfl_xor(cv, 2);  cc += __shfl_xor(cc, 2);
        cv += __shfl_xor(cv, 4);  cc += __shfl_xor(cc, 4);
        cv += __shfl_xor(cv, 8);  cc += __shfl_xor(cc, 8);
        cv += __shfl_xor(cv, 16); cc += __shfl_xor(cc, 16);
        cv += __shfl_xor(cv, 32); cc += __shfl_xor(cc, 32);
        if (t == 0) {
            atomicAdd(&accum[0], cv);
            atomicAdd(&accum[1], cc);
        }
    }
}

// ---------------- finalize: loss = sum / max(count,1) -> float32 out ----------------
__global__ void final_k(const float* __restrict__ accum, float* __restrict__ out) {
    if (threadIdx.x == 0 && blockIdx.x == 0) {
        out[0] = accum[0] / fmaxf(accum[1], 1.0f);
    }
}

extern "C" void kernel_launch(void* const* d_in, const int* in_sizes, int n_in,
                              void* d_out, int out_size, void* d_ws, size_t ws_size,
                              hipStream_t stream) {
    const float* feats_strong = (const float*)d_in[0];
    const float* feats_weak   = (const float*)d_in[1];
    const int*   s_lab        = (const int*)d_in[2];
    const int*   w_lab        = (const int*)d_in[3];
    const float* Wq           = (const float*)d_in[4];
    const float* bq           = (const float*)d_in[5];
    const float* Wk           = (const float*)d_in[6];
    const float* bk           = (const float*)d_in[7];
    const float* queue        = (const float*)d_in[8];

    float*    wsf = (float*)d_ws;
    int*      wsi = (int*)d_ws;

    float*    q_g   = wsf + OFF_Q;
    float*    k_g   = wsf + OFF_K;
    int*      table = wsi + OFF_TABLE;
    ushort_t* Wtq   = (ushort_t*)(wsi + OFF_WTQ);
    ushort_t* Wtk   = (ushort_t*)(wsi + OFF_WTK);
    int*      hist  = wsi + OFF_HIST;
    int*      rank  = wsi + OFF_RANK;
    int*      occ   = wsi + OFF_OCC;
    int*      idx   = wsi + OFF_IDX;
    float*    lpos  = wsf + OFF_LPOS;
    int*      bhs   = wsi + OFF_BHS;
    int*      bhw   = wsi + OFF_BHW;
    float*    accum = wsf + OFF_ACC;
    ushort_t* Qt    = (ushort_t*)(wsi + OFF_QT);

    // 1) convert/transpose weights + queue to bf16 (Wt aliases table region — used before table_k)
    cvt_k<<<dim3(128, 3), 256, 0, stream>>>(Wq, Wk, queue, Wtq, Wtk, Qt);

    // 2) both encoder GEMMs in one MFMA dispatch (256 blocks)
    enc_mfma_k<<<256, 256, 0, stream>>>(feats_weak, feats_strong, Wtq, Wtk, bq, bk, q_g, k_g);

    // 3) index-construction chain (clobbers Wt region via table_k — safe, enc done)
    zero_k<<<1, 128, 0, stream>>>(hist, accum);
    hist_k<<<NS / 256, 256, 0, stream>>>(s_lab, hist);
    blockhist_k<<<NS / 256, 256, 0, stream>>>(s_lab, bhs);
    rank_k<<<NS / 256, 256, 0, stream>>>(s_lab, bhs, occ);
    blockhist_k<<<NW / 256, 256, 0, stream>>>(w_lab, bhw);
    rank_k<<<NW / 256, 256, 0, stream>>>(w_lab, bhw, rank);
    table_k<<<NS / 256, 256, 0, stream>>>(s_lab, occ, table);
    idx_k<<<NW / 256, 256, 0, stream>>>(w_lab, rank, hist, table, idx);

    // 4) l_pos (fp32 exact), then fused l_neg GEMM + CE
    lpos_k<<<NW / 32, 256, 0, stream>>>(q_g, k_g, idx, lpos);
    ce_mfma_k<<<NW / 32, 256, 0, stream>>>(q_g, Qt, lpos, w_lab, hist, accum);
    final_k<<<1, 64, 0, stream>>>(accum, (float*)d_out);
}